// Round 4
// baseline (505.134 us; speedup 1.0000x reference)
//
#include <hip/hip_runtime.h>

typedef __bf16 bf16;
typedef short  s16;
typedef s16   s16x8 __attribute__((ext_vector_type(8)));   // 8 bf16 bit-patterns (4 VGPRs)
typedef bf16  bf16x4 __attribute__((ext_vector_type(4)));
typedef float f32x4 __attribute__((ext_vector_type(4)));

#define B_SZ 2
#define T_SEQ 2048
#define C_DIM 1024
#define NH 16
#define HS 64
#define M_TOT (B_SZ * T_SEQ)

#define NEG_BIG (-30000.0f)
#define LOG2_10000 13.287712379549449f

// Bit-level inf/NaN launder (immune to fast-math folding of x!=x).
__device__ __forceinline__ float san(float x) {
    unsigned u = __float_as_uint(x);
    return ((u & 0x7F800000u) == 0x7F800000u) ? 0.f : x;
}

// ---------------------------------------------------------------------------
// fp32 -> bf16 conversion. blockIdx.y: 0=x (4M elems), 1..4 = Wq,Wk,Wv,Wp (1M).
// ---------------------------------------------------------------------------
__global__ __launch_bounds__(256) void cvt_bf16_kernel(
    const float* __restrict__ x,  const float* __restrict__ wq,
    const float* __restrict__ wk, const float* __restrict__ wv,
    const float* __restrict__ wp,
    bf16* __restrict__ xb, bf16* __restrict__ wqb, bf16* __restrict__ wkb,
    bf16* __restrict__ wvb, bf16* __restrict__ wpb)
{
    const int z = blockIdx.y;
    const float* src = (z == 0) ? x : (z == 1) ? wq : (z == 2) ? wk : (z == 3) ? wv : wp;
    bf16* dst = (z == 0) ? xb : (z == 1) ? wqb : (z == 2) ? wkb : (z == 3) ? wvb : wpb;
    const int n = (z == 0) ? (M_TOT * C_DIM) : (C_DIM * C_DIM);

    const int i = (blockIdx.x * 256 + threadIdx.x) * 4;
    if (i >= n) return;
    const float4 v = *(const float4*)(src + i);
    bf16x4 o;
    o[0] = (bf16)v.x; o[1] = (bf16)v.y; o[2] = (bf16)v.z; o[3] = (bf16)v.w;
    *(bf16x4*)(dst + i) = o;
}

// ---------------------------------------------------------------------------
// RoPE table: cs/sn[t*32 + i] = cos/sin(t * 10000^(-2i/64)), t<2048, i<32.
// ---------------------------------------------------------------------------
__global__ __launch_bounds__(256) void rope_tab_kernel(float* __restrict__ cs,
                                                       float* __restrict__ sn)
{
    const int idx = blockIdx.x * 256 + threadIdx.x;   // 65536 total
    const int t = idx >> 5, i = idx & 31;
    const float theta = __builtin_exp2f(-(float)(2 * i) * (LOG2_10000 / 64.f));
    const float a = (float)t * theta;
    cs[idx] = san(cosf(a));
    sn[idx] = san(sinf(a));
}

// ---------------------------------------------------------------------------
// QKV projection: C = X @ W^T + b, fused RoPE (table) for Q/K.
// X: (4096,1024) bf16 (pre-converted). W: (1024,1024) bf16. b: fp32.
// blockIdx.z: 0=Q (rope), 1=K (rope), 2=V (store transposed).
// Q,K out: (B,NH,T,HS). V out: (B,NH,HS,T).
// Block 256 = 4 waves; tile 64x64; wave w owns rows w*16..+16.
// MFMA 16x16x32 bf16 (m89 layouts): A[m=lane&15][k=(lane>>4)*8+j];
// C/D: col=lane&15, row=(lane>>4)*4+reg.
// ---------------------------------------------------------------------------
__global__ __launch_bounds__(256) void qkv_gemm(
    const bf16* __restrict__ X,
    const bf16* __restrict__ Wq, const float* __restrict__ bq,
    const bf16* __restrict__ Wk, const float* __restrict__ bk,
    const bf16* __restrict__ Wv, const float* __restrict__ bv,
    const float* __restrict__ cs_tab, const float* __restrict__ sn_tab,
    bf16* __restrict__ q_ws, bf16* __restrict__ k_ws, bf16* __restrict__ vt_ws)
{
    const int mode = blockIdx.z;
    const bf16*  W    = (mode == 0) ? Wq : (mode == 1) ? Wk : Wv;
    const float* bias = (mode == 0) ? bq : (mode == 1) ? bk : bv;

    const int m0 = blockIdx.x * 64;
    const int n0 = blockIdx.y * 64;
    const int w    = threadIdx.x >> 6;
    const int lane = threadIdx.x & 63;
    const int qd = lane >> 4;
    const int r  = lane & 15;

    const bf16* xrow = X + (size_t)(m0 + w * 16 + r) * C_DIM;
    const bf16* wrow = W + (size_t)(n0 + r) * C_DIM;

    f32x4 acc[4] = {};

    #pragma unroll 4
    for (int k = 0; k < C_DIM; k += 32) {
        s16x8 a = *(const s16x8*)(xrow + k + qd * 8);
        #pragma unroll
        for (int nt = 0; nt < 4; nt++) {
            s16x8 b = *(const s16x8*)(wrow + (size_t)nt * 16 * C_DIM + k + qd * 8);
            acc[nt] = __builtin_amdgcn_mfma_f32_16x16x32_bf16(a, b, acc[nt], 0, 0, 0);
        }
    }

    const int mrow0 = m0 + w * 16 + qd * 4;     // + reg; 64-tiles never cross batch
    const int bb = mrow0 / T_SEQ;

    if (mode == 2) {
        // V: (B, NH, HS, T); 4 regs = 4 consecutive t -> one 8B store
        #pragma unroll
        for (int nt = 0; nt < 4; nt++) {
            const int col = n0 + nt * 16 + r;
            const int h = col >> 6, d = col & 63;
            const float bv_ = bias[col];
            const int t0 = mrow0 - bb * T_SEQ;
            bf16x4 pk;
            #pragma unroll
            for (int reg = 0; reg < 4; reg++) pk[reg] = (bf16)san(acc[nt][reg] + bv_);
            *(bf16x4*)(vt_ws + ((size_t)(bb * NH + h) * HS + d) * T_SEQ + t0) = pk;
        }
    } else {
        bf16* out = (mode == 0) ? q_ws : k_ws;
        #pragma unroll
        for (int nt = 0; nt < 4; nt++) {
            const int col = n0 + nt * 16 + r;
            const int h = col >> 6, d = col & 63;
            const int i = d >> 1;                 // pair index, same for lane pair
            const float bv_ = bias[col];
            #pragma unroll
            for (int reg = 0; reg < 4; reg++) {
                const int t = mrow0 + reg - bb * T_SEQ;
                float v = san(acc[nt][reg] + bv_);
                float partner = __shfl_xor(v, 1);  // lane col^1 = other pair half
                float c = cs_tab[t * 32 + i];
                float s = sn_tab[t * 32 + i];
                float rot = (d & 1) ? (v * c + partner * s)
                                    : (v * c - partner * s);
                out[((size_t)(bb * NH + h) * T_SEQ + t) * HS + d] = (bf16)san(rot);
            }
        }
    }
}

// ---------------------------------------------------------------------------
// Flash attention: block = (64 q-rows, one (b,h)). 4 waves, 16 q-rows each.
// Online softmax in registers; P: C-layout -> per-wave LDS -> A-layout.
// LDS rows padded to 72 elems (144B stride: 16B-aligned, bank stride 4).
// ---------------------------------------------------------------------------
__global__ __launch_bounds__(256) void attn_kernel(
    const bf16* __restrict__ q_ws, const bf16* __restrict__ k_ws,
    const bf16* __restrict__ vt_ws, bf16* __restrict__ y_ws)
{
    __shared__ __attribute__((aligned(16))) bf16 sK[64 * 72];
    __shared__ __attribute__((aligned(16))) bf16 sV[64 * 72];        // [d][t]
    __shared__ __attribute__((aligned(16))) bf16 sP[4 * 16 * 72];    // per-wave

    const int qt = blockIdx.x;
    const int bh = blockIdx.y;
    const int w    = threadIdx.x >> 6;
    const int lane = threadIdx.x & 63;
    const int qd = lane >> 4;
    const int r  = lane & 15;
    const int tid = threadIdx.x;

    const bf16* Qb = q_ws + (size_t)bh * T_SEQ * HS;
    const bf16* Kb = k_ws + (size_t)bh * T_SEQ * HS;
    const bf16* Vb = vt_ws + (size_t)bh * HS * T_SEQ;

    const int q0 = qt * 64 + w * 16;
    s16x8 aq0 = *(const s16x8*)(Qb + (size_t)(q0 + r) * HS + qd * 8);
    s16x8 aq1 = *(const s16x8*)(Qb + (size_t)(q0 + r) * HS + 32 + qd * 8);

    f32x4 o[4] = {};
    float m_i[4], l_i[4];
    #pragma unroll
    for (int j = 0; j < 4; j++) { m_i[j] = NEG_BIG; l_i[j] = 0.f; }

    const int ld_row = tid >> 3;        // 0..31
    const int ld_c8  = (tid & 7) * 8;   // 0..56
    bf16* pw = sP + w * 16 * 72;

    for (int kt = 0; kt <= qt; kt++) {
        __syncthreads();  // prior iteration's LDS reads complete
        *(s16x8*)(sK + ld_row * 72 + ld_c8) =
            *(const s16x8*)(Kb + (size_t)(kt * 64 + ld_row) * HS + ld_c8);
        *(s16x8*)(sK + (ld_row + 32) * 72 + ld_c8) =
            *(const s16x8*)(Kb + (size_t)(kt * 64 + ld_row + 32) * HS + ld_c8);
        *(s16x8*)(sV + ld_row * 72 + ld_c8) =
            *(const s16x8*)(Vb + (size_t)ld_row * T_SEQ + kt * 64 + ld_c8);
        *(s16x8*)(sV + (ld_row + 32) * 72 + ld_c8) =
            *(const s16x8*)(Vb + (size_t)(ld_row + 32) * T_SEQ + kt * 64 + ld_c8);
        __syncthreads();

        // S = Q K^T (16 q-rows x 64 k-cols per wave)
        f32x4 s[4];
        #pragma unroll
        for (int nt = 0; nt < 4; nt++) {
            s16x8 b0 = *(const s16x8*)(sK + (nt * 16 + r) * 72 + qd * 8);
            s16x8 b1 = *(const s16x8*)(sK + (nt * 16 + r) * 72 + 32 + qd * 8);
            f32x4 z = {};
            z = __builtin_amdgcn_mfma_f32_16x16x32_bf16(aq0, b0, z, 0, 0, 0);
            z = __builtin_amdgcn_mfma_f32_16x16x32_bf16(aq1, b1, z, 0, 0, 0);
            s[nt] = z;
        }

        const float scale = 0.125f;  // 1/sqrt(64)
        if (kt == qt) {
            #pragma unroll
            for (int nt = 0; nt < 4; nt++)
                #pragma unroll
                for (int reg = 0; reg < 4; reg++) {
                    const int qg = q0 + qd * 4 + reg;
                    const int kg = kt * 64 + nt * 16 + r;
                    s[nt][reg] = (kg <= qg) ? s[nt][reg] * scale : NEG_BIG;
                }
        } else {
            #pragma unroll
            for (int nt = 0; nt < 4; nt++)
                #pragma unroll
                for (int reg = 0; reg < 4; reg++) s[nt][reg] *= scale;
        }

        // online softmax: row = qd*4+reg; cols split over nt x 16 lanes (same qd)
        float mnew[4], alpha[4], rs[4];
        #pragma unroll
        for (int reg = 0; reg < 4; reg++) {
            float mx = fmaxf(fmaxf(s[0][reg], s[1][reg]), fmaxf(s[2][reg], s[3][reg]));
            mx = fmaxf(mx, __shfl_xor(mx, 1));
            mx = fmaxf(mx, __shfl_xor(mx, 2));
            mx = fmaxf(mx, __shfl_xor(mx, 4));
            mx = fmaxf(mx, __shfl_xor(mx, 8));
            mnew[reg] = fmaxf(m_i[reg], mx);
            alpha[reg] = __expf(fminf(m_i[reg] - mnew[reg], 0.f));
            m_i[reg] = mnew[reg];
            rs[reg] = 0.f;
        }
        #pragma unroll
        for (int nt = 0; nt < 4; nt++)
            #pragma unroll
            for (int reg = 0; reg < 4; reg++) {
                float p = __expf(fminf(s[nt][reg] - mnew[reg], 0.f));
                s[nt][reg] = p;
                rs[reg] += p;
            }
        #pragma unroll
        for (int reg = 0; reg < 4; reg++) {
            float t = rs[reg];
            t += __shfl_xor(t, 1); t += __shfl_xor(t, 2);
            t += __shfl_xor(t, 4); t += __shfl_xor(t, 8);
            l_i[reg] = l_i[reg] * alpha[reg] + t;
        }
        #pragma unroll
        for (int nt = 0; nt < 4; nt++)
            #pragma unroll
            for (int reg = 0; reg < 4; reg++) o[nt][reg] *= alpha[reg];

        // P: C-layout -> LDS -> A-layout (per-wave region, m120 pattern)
        #pragma unroll
        for (int nt = 0; nt < 4; nt++)
            #pragma unroll
            for (int reg = 0; reg < 4; reg++)
                pw[(qd * 4 + reg) * 72 + nt * 16 + r] = (bf16)s[nt][reg];
        __syncthreads();

        s16x8 ap0 = *(const s16x8*)(pw + r * 72 + qd * 8);
        s16x8 ap1 = *(const s16x8*)(pw + r * 72 + 32 + qd * 8);
        #pragma unroll
        for (int nt = 0; nt < 4; nt++) {
            s16x8 bv0 = *(const s16x8*)(sV + (nt * 16 + r) * 72 + qd * 8);
            s16x8 bv1 = *(const s16x8*)(sV + (nt * 16 + r) * 72 + 32 + qd * 8);
            o[nt] = __builtin_amdgcn_mfma_f32_16x16x32_bf16(ap0, bv0, o[nt], 0, 0, 0);
            o[nt] = __builtin_amdgcn_mfma_f32_16x16x32_bf16(ap1, bv1, o[nt], 0, 0, 0);
        }
    }

    // epilogue: y (B, T, NH, HS)
    const int bb = bh >> 4, h = bh & 15;
    #pragma unroll
    for (int reg = 0; reg < 4; reg++) {
        const int t = q0 + qd * 4 + reg;
        const float inv = 1.f / fmaxf(l_i[reg], 1e-20f);
        bf16* dst = y_ws + ((size_t)(bb * T_SEQ + t) * NH + h) * HS;
        #pragma unroll
        for (int nt = 0; nt < 4; nt++)
            dst[nt * 16 + r] = (bf16)san(o[nt][reg] * inv);
    }
}

// ---------------------------------------------------------------------------
// Output projection: out = Y @ Wp^T + bp. Y bf16, Wp bf16, bp fp32, out FP32.
// ---------------------------------------------------------------------------
__global__ __launch_bounds__(256) void proj_gemm(
    const bf16* __restrict__ Y, const bf16* __restrict__ Wp,
    const float* __restrict__ bp, float* __restrict__ out)
{
    const int m0 = blockIdx.x * 64;
    const int n0 = blockIdx.y * 64;
    const int w    = threadIdx.x >> 6;
    const int lane = threadIdx.x & 63;
    const int qd = lane >> 4;
    const int r  = lane & 15;

    const bf16* xrow = Y + (size_t)(m0 + w * 16 + r) * C_DIM;
    const bf16* wrow = Wp + (size_t)(n0 + r) * C_DIM;

    f32x4 acc[4] = {};
    #pragma unroll 4
    for (int k = 0; k < C_DIM; k += 32) {
        s16x8 a = *(const s16x8*)(xrow + k + qd * 8);
        #pragma unroll
        for (int nt = 0; nt < 4; nt++) {
            s16x8 b = *(const s16x8*)(wrow + (size_t)nt * 16 * C_DIM + k + qd * 8);
            acc[nt] = __builtin_amdgcn_mfma_f32_16x16x32_bf16(a, b, acc[nt], 0, 0, 0);
        }
    }

    const int mrow0 = m0 + w * 16 + qd * 4;
    #pragma unroll
    for (int nt = 0; nt < 4; nt++) {
        const int col = n0 + nt * 16 + r;
        const float bv_ = bp[col];
        #pragma unroll
        for (int reg = 0; reg < 4; reg++)
            out[(size_t)(mrow0 + reg) * C_DIM + col] = san(acc[nt][reg] + bv_);
    }
}

// ---------------------------------------------------------------------------
extern "C" void kernel_launch(void* const* d_in, const int* in_sizes, int n_in,
                              void* d_out, int out_size, void* d_ws, size_t ws_size,
                              hipStream_t stream)
{
    // Workspace layout (MB offsets):
    //   0  q_ws  (B,NH,T,HS) bf16 8MB   | 24 x_b (4096,1024) bf16 8MB, later y_ws
    //   8  k_ws  (B,NH,T,HS) bf16 8MB   | 32 Wq_b 2MB  34 Wk_b 2MB
    //   16 vt_ws (B,NH,HS,T) bf16 8MB   | 36 Wv_b 2MB  38 Wp_b 2MB
    //   40 cs_tab 256KB, sn_tab 256KB
    const size_t MB = 1024 * 1024;
    const size_t NEED = 40 * MB + 2 * 65536 * sizeof(float);
    if (ws_size < NEED || n_in < 9) return;  // diagnostic signature: absmax == 4.40625

    const float* x  = (const float*)d_in[0];
    const float* Wq = (const float*)d_in[1];
    const float* bq = (const float*)d_in[2];
    const float* Wk = (const float*)d_in[3];
    const float* bk = (const float*)d_in[4];
    const float* Wv = (const float*)d_in[5];
    const float* bv = (const float*)d_in[6];
    const float* Wp = (const float*)d_in[7];
    const float* bp = (const float*)d_in[8];
    float* out = (float*)d_out;

    char* ws = (char*)d_ws;
    bf16*  q_ws   = (bf16*)(ws + 0 * MB);
    bf16*  k_ws   = (bf16*)(ws + 8 * MB);
    bf16*  vt_ws  = (bf16*)(ws + 16 * MB);
    bf16*  x_b    = (bf16*)(ws + 24 * MB);   // aliased: y_ws after qkv_gemm is done
    bf16*  y_ws   = (bf16*)(ws + 24 * MB);
    bf16*  Wq_b   = (bf16*)(ws + 32 * MB);
    bf16*  Wk_b   = (bf16*)(ws + 34 * MB);
    bf16*  Wv_b   = (bf16*)(ws + 36 * MB);
    bf16*  Wp_b   = (bf16*)(ws + 38 * MB);
    float* cs_tab = (float*)(ws + 40 * MB);
    float* sn_tab = cs_tab + 65536;

    cvt_bf16_kernel<<<dim3(M_TOT * C_DIM / 4 / 256, 5), 256, 0, stream>>>(
        x, Wq, Wk, Wv, Wp, x_b, Wq_b, Wk_b, Wv_b, Wp_b);
    rope_tab_kernel<<<dim3(65536 / 256), 256, 0, stream>>>(cs_tab, sn_tab);
    qkv_gemm<<<dim3(M_TOT / 64, C_DIM / 64, 3), 256, 0, stream>>>(
        x_b, Wq_b, bq, Wk_b, bk, Wv_b, bv, cs_tab, sn_tab, q_ws, k_ws, vt_ws);
    attn_kernel<<<dim3(T_SEQ / 64, B_SZ * NH), 256, 0, stream>>>(
        q_ws, k_ws, vt_ws, y_ws);
    proj_gemm<<<dim3(M_TOT / 64, C_DIM / 64), 256, 0, stream>>>(
        y_ws, Wp_b, bp, out);
}

// Round 5
// 285.614 us; speedup vs baseline: 1.7686x; 1.7686x over previous
//
#include <hip/hip_runtime.h>

typedef __bf16 bf16;
typedef short  s16;
typedef s16   s16x8 __attribute__((ext_vector_type(8)));   // 8 bf16 bit-patterns (4 VGPRs)
typedef bf16  bf16x4 __attribute__((ext_vector_type(4)));
typedef float f32x4 __attribute__((ext_vector_type(4)));

#define B_SZ 2
#define T_SEQ 2048
#define C_DIM 1024
#define NH 16
#define HS 64
#define M_TOT (B_SZ * T_SEQ)

#define NEG_BIG (-30000.0f)
#define LOG2_10000 13.287712379549449f

__device__ __forceinline__ float san(float x) {
    unsigned u = __float_as_uint(x);
    return ((u & 0x7F800000u) == 0x7F800000u) ? 0.f : x;
}

// async global->LDS, 16B per lane; lds base must be wave-uniform (HW adds lane*16)
__device__ __forceinline__ void load16_lds(const bf16* g, void* lds_base) {
    __builtin_amdgcn_global_load_lds(
        (const __attribute__((address_space(1))) void*)g,
        (__attribute__((address_space(3))) void*)lds_base, 16, 0, 0);
}

// ---------------------------------------------------------------------------
// fp32 -> bf16 conversion. blockIdx.y: 0=x (4M elems), 1..4 = Wq,Wk,Wv,Wp (1M).
// ---------------------------------------------------------------------------
__global__ __launch_bounds__(256) void cvt_bf16_kernel(
    const float* __restrict__ x,  const float* __restrict__ wq,
    const float* __restrict__ wk, const float* __restrict__ wv,
    const float* __restrict__ wp,
    bf16* __restrict__ xb, bf16* __restrict__ wqb, bf16* __restrict__ wkb,
    bf16* __restrict__ wvb, bf16* __restrict__ wpb)
{
    const int z = blockIdx.y;
    const float* src = (z == 0) ? x : (z == 1) ? wq : (z == 2) ? wk : (z == 3) ? wv : wp;
    bf16* dst = (z == 0) ? xb : (z == 1) ? wqb : (z == 2) ? wkb : (z == 3) ? wvb : wpb;
    const int n = (z == 0) ? (M_TOT * C_DIM) : (C_DIM * C_DIM);

    const int i = (blockIdx.x * 256 + threadIdx.x) * 4;
    if (i >= n) return;
    const float4 v = *(const float4*)(src + i);
    bf16x4 o;
    o[0] = (bf16)v.x; o[1] = (bf16)v.y; o[2] = (bf16)v.z; o[3] = (bf16)v.w;
    *(bf16x4*)(dst + i) = o;
}

// ---------------------------------------------------------------------------
// RoPE table: cs/sn[t*32 + i] = cos/sin(t * 10000^(-2i/64)).
// ---------------------------------------------------------------------------
__global__ __launch_bounds__(256) void rope_tab_kernel(float* __restrict__ cs,
                                                       float* __restrict__ sn)
{
    const int idx = blockIdx.x * 256 + threadIdx.x;   // 65536 total
    const int t = idx >> 5, i = idx & 31;
    const float theta = __builtin_exp2f(-(float)(2 * i) * (LOG2_10000 / 64.f));
    const float a = (float)t * theta;
    cs[idx] = san(cosf(a));
    sn[idx] = san(sinf(a));
}

// ---------------------------------------------------------------------------
// m97-style GEMM core: 128x128 tile, BK=32, 4 waves (2x2), global_load_lds
// staging into unpadded [128][32] LDS; 16 MFMA + 8 ds_read_b128 per K-step.
// Computes acc[mt][nt] for rows m0+wm*64+mt*16+qd*4+reg, cols n0+wn*64+nt*16+r.
// ---------------------------------------------------------------------------
#define GEMM_CORE(Xp, Wp_)                                                     \
    const int t = threadIdx.x;                                                 \
    const int w = t >> 6;                                                      \
    const int lane = t & 63;                                                   \
    const int qd = lane >> 4;                                                  \
    const int r  = lane & 15;                                                  \
    const int wm = w & 1, wn = w >> 1;                                         \
    const int srow = t >> 2;                                                   \
    const int scol = (t & 3) * 8;                                              \
    const bf16* gA0 = (Xp) + (size_t)(m0 + srow) * C_DIM + scol;               \
    const bf16* gA1 = (Xp) + (size_t)(m0 + 64 + srow) * C_DIM + scol;          \
    const bf16* gB0 = (Wp_) + (size_t)(n0 + srow) * C_DIM + scol;              \
    const bf16* gB1 = (Wp_) + (size_t)(n0 + 64 + srow) * C_DIM + scol;         \
    char* ldsA0 = (char*)sA + (size_t)(w * 64) * 16;                           \
    char* ldsA1 = (char*)sA + (size_t)(256 + w * 64) * 16;                     \
    char* ldsB0 = (char*)sB + (size_t)(w * 64) * 16;                           \
    char* ldsB1 = (char*)sB + (size_t)(256 + w * 64) * 16;                     \
    f32x4 acc[4][4] = {};                                                      \
    for (int k0 = 0; k0 < C_DIM; k0 += 32) {                                   \
        __syncthreads();                                                       \
        load16_lds(gA0 + k0, ldsA0);                                           \
        load16_lds(gA1 + k0, ldsA1);                                           \
        load16_lds(gB0 + k0, ldsB0);                                           \
        load16_lds(gB1 + k0, ldsB1);                                           \
        __syncthreads();                                                       \
        s16x8 af[4], bfr[4];                                                   \
        _Pragma("unroll")                                                      \
        for (int mt = 0; mt < 4; mt++)                                         \
            af[mt] = *(const s16x8*)(sA + (wm * 64 + mt * 16 + r) * 32 + qd * 8); \
        _Pragma("unroll")                                                      \
        for (int nt = 0; nt < 4; nt++)                                         \
            bfr[nt] = *(const s16x8*)(sB + (wn * 64 + nt * 16 + r) * 32 + qd * 8); \
        _Pragma("unroll")                                                      \
        for (int mt = 0; mt < 4; mt++)                                         \
            _Pragma("unroll")                                                  \
            for (int nt = 0; nt < 4; nt++)                                     \
                acc[mt][nt] = __builtin_amdgcn_mfma_f32_16x16x32_bf16(         \
                    af[mt], bfr[nt], acc[mt][nt], 0, 0, 0);                    \
    }

// ---------------------------------------------------------------------------
// QKV projection + fused RoPE (Q/K) / transpose-store (V).
// blockIdx.z: 0=Q, 1=K, 2=V. Q,K out (B,NH,T,HS); V out (B,NH,HS,T).
// ---------------------------------------------------------------------------
__global__ __launch_bounds__(256) void qkv_gemm(
    const bf16* __restrict__ X,
    const bf16* __restrict__ Wq, const float* __restrict__ bq,
    const bf16* __restrict__ Wk, const float* __restrict__ bk,
    const bf16* __restrict__ Wv, const float* __restrict__ bv,
    const float* __restrict__ cs_tab, const float* __restrict__ sn_tab,
    bf16* __restrict__ q_ws, bf16* __restrict__ k_ws, bf16* __restrict__ vt_ws)
{
    __shared__ __attribute__((aligned(16))) bf16 sA[128 * 32];
    __shared__ __attribute__((aligned(16))) bf16 sB[128 * 32];

    const int mode = blockIdx.z;
    const bf16*  Wm   = (mode == 0) ? Wq : (mode == 1) ? Wk : Wv;
    const float* bias = (mode == 0) ? bq : (mode == 1) ? bk : bv;
    const int m0 = blockIdx.x * 128;
    const int n0 = blockIdx.y * 128;

    GEMM_CORE(X, Wm)

    // epilogue: row = m0+wm*64+mt*16+qd*4+reg (within one batch: 128 | 2048)
    if (mode == 2) {
        #pragma unroll
        for (int mt = 0; mt < 4; mt++) {
            const int mrow0 = m0 + wm * 64 + mt * 16 + qd * 4;
            const int bb = mrow0 >> 11;
            const int t0 = mrow0 & 2047;
            #pragma unroll
            for (int nt = 0; nt < 4; nt++) {
                const int col = n0 + wn * 64 + nt * 16 + r;
                const int h = col >> 6, d = col & 63;
                const float bv_ = bias[col];
                bf16x4 pk;
                #pragma unroll
                for (int reg = 0; reg < 4; reg++)
                    pk[reg] = (bf16)san(acc[mt][nt][reg] + bv_);
                *(bf16x4*)(vt_ws + ((size_t)(bb * NH + h) * HS + d) * T_SEQ + t0) = pk;
            }
        }
    } else {
        bf16* out = (mode == 0) ? q_ws : k_ws;
        #pragma unroll
        for (int mt = 0; mt < 4; mt++) {
            const int mrow0 = m0 + wm * 64 + mt * 16 + qd * 4;
            const int bb = mrow0 >> 11;
            const int t0 = mrow0 & 2047;
            #pragma unroll
            for (int nt = 0; nt < 4; nt++) {
                const int col = n0 + wn * 64 + nt * 16 + r;
                const int h = col >> 6, d = col & 63;
                const int pi = d >> 1;              // rope pair index
                const float bv_ = bias[col];
                #pragma unroll
                for (int reg = 0; reg < 4; reg++) {
                    const int tt = t0 + reg;
                    float v = san(acc[mt][nt][reg] + bv_);
                    float partner = __shfl_xor(v, 1);   // lane col^1
                    float c = cs_tab[tt * 32 + pi];
                    float s = sn_tab[tt * 32 + pi];
                    float rot = (d & 1) ? (v * c + partner * s)
                                        : (v * c - partner * s);
                    out[((size_t)(bb * NH + h) * T_SEQ + tt) * HS + d] = (bf16)san(rot);
                }
            }
        }
    }
}

// ---------------------------------------------------------------------------
// Output projection: out = Y @ Wp^T + bp (fp32 out).
// ---------------------------------------------------------------------------
__global__ __launch_bounds__(256) void proj_gemm(
    const bf16* __restrict__ Y, const bf16* __restrict__ Wp,
    const float* __restrict__ bp, float* __restrict__ out)
{
    __shared__ __attribute__((aligned(16))) bf16 sA[128 * 32];
    __shared__ __attribute__((aligned(16))) bf16 sB[128 * 32];

    const int m0 = blockIdx.x * 128;
    const int n0 = blockIdx.y * 128;

    GEMM_CORE(Y, Wp)

    #pragma unroll
    for (int mt = 0; mt < 4; mt++) {
        const int mrow0 = m0 + wm * 64 + mt * 16 + qd * 4;
        #pragma unroll
        for (int nt = 0; nt < 4; nt++) {
            const int col = n0 + wn * 64 + nt * 16 + r;
            const float bv_ = bp[col];
            #pragma unroll
            for (int reg = 0; reg < 4; reg++)
                out[(size_t)(mrow0 + reg) * C_DIM + col] = san(acc[mt][nt][reg] + bv_);
        }
    }
}

// ---------------------------------------------------------------------------
// Flash attention (unchanged from round 4): block = (64 q-rows, one (b,h)).
// ---------------------------------------------------------------------------
__global__ __launch_bounds__(256) void attn_kernel(
    const bf16* __restrict__ q_ws, const bf16* __restrict__ k_ws,
    const bf16* __restrict__ vt_ws, bf16* __restrict__ y_ws)
{
    __shared__ __attribute__((aligned(16))) bf16 sK[64 * 72];
    __shared__ __attribute__((aligned(16))) bf16 sV[64 * 72];        // [d][t]
    __shared__ __attribute__((aligned(16))) bf16 sP[4 * 16 * 72];    // per-wave

    const int qt = blockIdx.x;
    const int bh = blockIdx.y;
    const int w    = threadIdx.x >> 6;
    const int lane = threadIdx.x & 63;
    const int qd = lane >> 4;
    const int r  = lane & 15;
    const int tid = threadIdx.x;

    const bf16* Qb = q_ws + (size_t)bh * T_SEQ * HS;
    const bf16* Kb = k_ws + (size_t)bh * T_SEQ * HS;
    const bf16* Vb = vt_ws + (size_t)bh * HS * T_SEQ;

    const int q0 = qt * 64 + w * 16;
    s16x8 aq0 = *(const s16x8*)(Qb + (size_t)(q0 + r) * HS + qd * 8);
    s16x8 aq1 = *(const s16x8*)(Qb + (size_t)(q0 + r) * HS + 32 + qd * 8);

    f32x4 o[4] = {};
    float m_i[4], l_i[4];
    #pragma unroll
    for (int j = 0; j < 4; j++) { m_i[j] = NEG_BIG; l_i[j] = 0.f; }

    const int ld_row = tid >> 3;        // 0..31
    const int ld_c8  = (tid & 7) * 8;   // 0..56
    bf16* pw = sP + w * 16 * 72;

    for (int kt = 0; kt <= qt; kt++) {
        __syncthreads();
        *(s16x8*)(sK + ld_row * 72 + ld_c8) =
            *(const s16x8*)(Kb + (size_t)(kt * 64 + ld_row) * HS + ld_c8);
        *(s16x8*)(sK + (ld_row + 32) * 72 + ld_c8) =
            *(const s16x8*)(Kb + (size_t)(kt * 64 + ld_row + 32) * HS + ld_c8);
        *(s16x8*)(sV + ld_row * 72 + ld_c8) =
            *(const s16x8*)(Vb + (size_t)ld_row * T_SEQ + kt * 64 + ld_c8);
        *(s16x8*)(sV + (ld_row + 32) * 72 + ld_c8) =
            *(const s16x8*)(Vb + (size_t)(ld_row + 32) * T_SEQ + kt * 64 + ld_c8);
        __syncthreads();

        f32x4 s[4];
        #pragma unroll
        for (int nt = 0; nt < 4; nt++) {
            s16x8 b0 = *(const s16x8*)(sK + (nt * 16 + r) * 72 + qd * 8);
            s16x8 b1 = *(const s16x8*)(sK + (nt * 16 + r) * 72 + 32 + qd * 8);
            f32x4 z = {};
            z = __builtin_amdgcn_mfma_f32_16x16x32_bf16(aq0, b0, z, 0, 0, 0);
            z = __builtin_amdgcn_mfma_f32_16x16x32_bf16(aq1, b1, z, 0, 0, 0);
            s[nt] = z;
        }

        const float scale = 0.125f;  // 1/sqrt(64)
        if (kt == qt) {
            #pragma unroll
            for (int nt = 0; nt < 4; nt++)
                #pragma unroll
                for (int reg = 0; reg < 4; reg++) {
                    const int qg = q0 + qd * 4 + reg;
                    const int kg = kt * 64 + nt * 16 + r;
                    s[nt][reg] = (kg <= qg) ? s[nt][reg] * scale : NEG_BIG;
                }
        } else {
            #pragma unroll
            for (int nt = 0; nt < 4; nt++)
                #pragma unroll
                for (int reg = 0; reg < 4; reg++) s[nt][reg] *= scale;
        }

        float mnew[4], alpha[4], rs[4];
        #pragma unroll
        for (int reg = 0; reg < 4; reg++) {
            float mx = fmaxf(fmaxf(s[0][reg], s[1][reg]), fmaxf(s[2][reg], s[3][reg]));
            mx = fmaxf(mx, __shfl_xor(mx, 1));
            mx = fmaxf(mx, __shfl_xor(mx, 2));
            mx = fmaxf(mx, __shfl_xor(mx, 4));
            mx = fmaxf(mx, __shfl_xor(mx, 8));
            mnew[reg] = fmaxf(m_i[reg], mx);
            alpha[reg] = __expf(fminf(m_i[reg] - mnew[reg], 0.f));
            m_i[reg] = mnew[reg];
            rs[reg] = 0.f;
        }
        #pragma unroll
        for (int nt = 0; nt < 4; nt++)
            #pragma unroll
            for (int reg = 0; reg < 4; reg++) {
                float p = __expf(fminf(s[nt][reg] - mnew[reg], 0.f));
                s[nt][reg] = p;
                rs[reg] += p;
            }
        #pragma unroll
        for (int reg = 0; reg < 4; reg++) {
            float t = rs[reg];
            t += __shfl_xor(t, 1); t += __shfl_xor(t, 2);
            t += __shfl_xor(t, 4); t += __shfl_xor(t, 8);
            l_i[reg] = l_i[reg] * alpha[reg] + t;
        }
        #pragma unroll
        for (int nt = 0; nt < 4; nt++)
            #pragma unroll
            for (int reg = 0; reg < 4; reg++) o[nt][reg] *= alpha[reg];

        #pragma unroll
        for (int nt = 0; nt < 4; nt++)
            #pragma unroll
            for (int reg = 0; reg < 4; reg++)
                pw[(qd * 4 + reg) * 72 + nt * 16 + r] = (bf16)s[nt][reg];
        __syncthreads();

        s16x8 ap0 = *(const s16x8*)(pw + r * 72 + qd * 8);
        s16x8 ap1 = *(const s16x8*)(pw + r * 72 + 32 + qd * 8);
        #pragma unroll
        for (int nt = 0; nt < 4; nt++) {
            s16x8 bv0 = *(const s16x8*)(sV + (nt * 16 + r) * 72 + qd * 8);
            s16x8 bv1 = *(const s16x8*)(sV + (nt * 16 + r) * 72 + 32 + qd * 8);
            o[nt] = __builtin_amdgcn_mfma_f32_16x16x32_bf16(ap0, bv0, o[nt], 0, 0, 0);
            o[nt] = __builtin_amdgcn_mfma_f32_16x16x32_bf16(ap1, bv1, o[nt], 0, 0, 0);
        }
    }

    const int bb = bh >> 4, h = bh & 15;
    #pragma unroll
    for (int reg = 0; reg < 4; reg++) {
        const int t = q0 + qd * 4 + reg;
        const float inv = 1.f / fmaxf(l_i[reg], 1e-20f);
        bf16* dst = y_ws + ((size_t)(bb * T_SEQ + t) * NH + h) * HS;
        #pragma unroll
        for (int nt = 0; nt < 4; nt++)
            dst[nt * 16 + r] = (bf16)san(o[nt][reg] * inv);
    }
}

// ---------------------------------------------------------------------------
extern "C" void kernel_launch(void* const* d_in, const int* in_sizes, int n_in,
                              void* d_out, int out_size, void* d_ws, size_t ws_size,
                              hipStream_t stream)
{
    // Workspace (MB offsets):
    //   0 q_ws 8 | 8 k_ws 8 | 16 vt_ws 8 | 24 x_b / y_ws 8
    //   32 Wq_b 2 | 34 Wk_b 2 | 36 Wv_b 2 | 38 Wp_b 2 | 40 cs/sn tabs 512KB
    const size_t MB = 1024 * 1024;
    const size_t NEED = 40 * MB + 2 * 65536 * sizeof(float);
    if (ws_size < NEED || n_in < 9) return;  // signature: absmax == 4.40625

    const float* x  = (const float*)d_in[0];
    const float* Wq = (const float*)d_in[1];
    const float* bq = (const float*)d_in[2];
    const float* Wk = (const float*)d_in[3];
    const float* bk = (const float*)d_in[4];
    const float* Wv = (const float*)d_in[5];
    const float* bv = (const float*)d_in[6];
    const float* Wp = (const float*)d_in[7];
    const float* bp = (const float*)d_in[8];
    float* out = (float*)d_out;

    char* ws = (char*)d_ws;
    bf16*  q_ws   = (bf16*)(ws + 0 * MB);
    bf16*  k_ws   = (bf16*)(ws + 8 * MB);
    bf16*  vt_ws  = (bf16*)(ws + 16 * MB);
    bf16*  x_b    = (bf16*)(ws + 24 * MB);   // aliased with y_ws (x_b dead by attn)
    bf16*  y_ws   = (bf16*)(ws + 24 * MB);
    bf16*  Wq_b   = (bf16*)(ws + 32 * MB);
    bf16*  Wk_b   = (bf16*)(ws + 34 * MB);
    bf16*  Wv_b   = (bf16*)(ws + 36 * MB);
    bf16*  Wp_b   = (bf16*)(ws + 38 * MB);
    float* cs_tab = (float*)(ws + 40 * MB);
    float* sn_tab = cs_tab + 65536;

    cvt_bf16_kernel<<<dim3(M_TOT * C_DIM / 4 / 256, 5), 256, 0, stream>>>(
        x, Wq, Wk, Wv, Wp, x_b, Wq_b, Wk_b, Wv_b, Wp_b);
    rope_tab_kernel<<<dim3(65536 / 256), 256, 0, stream>>>(cs_tab, sn_tab);
    qkv_gemm<<<dim3(M_TOT / 128, C_DIM / 128, 3), 256, 0, stream>>>(
        x_b, Wq_b, bq, Wk_b, bk, Wv_b, bv, cs_tab, sn_tab, q_ws, k_ws, vt_ws);
    attn_kernel<<<dim3(T_SEQ / 64, B_SZ * NH), 256, 0, stream>>>(
        q_ws, k_ws, vt_ws, y_ws);
    proj_gemm<<<dim3(M_TOT / 128, C_DIM / 128), 256, 0, stream>>>(
        y_ws, Wp_b, bp, out);
}